// Round 9
// baseline (132.103 us; speedup 1.0000x reference)
//
#include <hip/hip_runtime.h>
#include <math.h>

#define WPB 4   // 4 waves per block, 1 trajectory per wave

static __device__ __forceinline__ float frcp(float x){ return __builtin_amdgcn_rcpf(x); }
static __device__ __forceinline__ float fsq (float x){ return __builtin_amdgcn_sqrtf(x); }
static __device__ __forceinline__ float rld(float x, int l){
  return __uint_as_float(__builtin_amdgcn_readlane(__float_as_uint(x), l));
}

// ---- 6-step DPP wave64 reductions; result valid on lane 63 ONLY (no broadcast) ----
template<int CTRL, int RM>
static __device__ __forceinline__ float dppadd(float x){
  int t = __builtin_amdgcn_update_dpp(0, __float_as_int(x), CTRL, RM, 0xf, true);
  return x + __int_as_float(t);
}
template<int CTRL, int RM>
static __device__ __forceinline__ float dppmax(float x){
  int t = __builtin_amdgcn_update_dpp(__float_as_int(x), __float_as_int(x), CTRL, RM, 0xf, false);
  return fmaxf(x, __int_as_float(t));
}
template<int CTRL, int RM>
static __device__ __forceinline__ float dppmin(float x){
  int t = __builtin_amdgcn_update_dpp(__float_as_int(x), __float_as_int(x), CTRL, RM, 0xf, false);
  return fminf(x, __int_as_float(t));
}
static __device__ __forceinline__ float wsum63(float x){
  x = dppadd<0x111,0xf>(x); x = dppadd<0x112,0xf>(x);
  x = dppadd<0x114,0xf>(x); x = dppadd<0x118,0xf>(x);
  x = dppadd<0x142,0xa>(x); x = dppadd<0x143,0xc>(x);
  return x;                                   // lane 63 holds the total
}
static __device__ __forceinline__ float wmax63(float x){
  x = dppmax<0x111,0xf>(x); x = dppmax<0x112,0xf>(x);
  x = dppmax<0x114,0xf>(x); x = dppmax<0x118,0xf>(x);
  x = dppmax<0x142,0xa>(x); x = dppmax<0x143,0xc>(x);
  return x;
}
static __device__ __forceinline__ float wmin63(float x){
  x = dppmin<0x111,0xf>(x); x = dppmin<0x112,0xf>(x);
  x = dppmin<0x114,0xf>(x); x = dppmin<0x118,0xf>(x);
  x = dppmin<0x142,0xa>(x); x = dppmin<0x143,0xc>(x);
  return x;
}

__global__ void transpose_w(const float* __restrict__ W, float* __restrict__ Wt){
  int idx = blockIdx.x * 256 + threadIdx.x;
  if (idx < 60 * 48) { int f = idx / 48, j = idx - f * 48; Wt[j * 60 + f] = W[idx]; }
}

template<bool USEWT>
__global__ __launch_bounds__(WPB * 64)
void traj_kernel(const float* __restrict__ coords,
                 const int* __restrict__ lengths,
                 const float* __restrict__ Wsrc,   // Wt [48][60] if USEWT else W [60][48]
                 const float* __restrict__ bias,
                 const float* __restrict__ lnw,
                 const float* __restrict__ lnb,
                 float* __restrict__ out, int B)
{
  const int i = threadIdx.x & 63;                      // lane = row / delta index
  const int b = blockIdx.x * WPB + (threadIdx.x >> 6); // trajectory
  if (b >= B) return;

  const int n = __builtin_amdgcn_readfirstlane(lengths[b]); // wave-uniform, 4..48
  const int m = n - 1;                                      // 3..47
  const int half = m >> 1;
  const float* cp = coords + (size_t)b * 480;

  // ---- load rows j=min(i,47), j+1, j+2 (clamped; garbage masked downstream) ----
  const int r0 = (i < 47) ? i : 47;
  const int r1 = (i + 1 < 47) ? (i + 1) : 47;
  const int r2 = (i + 2 < 47) ? (i + 2) : 47;
  float c[10], cn[10], cnn[10];
  {
    const float2* p = reinterpret_cast<const float2*>(cp + r0 * 10);
#pragma unroll
    for (int k = 0; k < 5; ++k){ float2 v = p[k]; c[2*k]=v.x; c[2*k+1]=v.y; }
    p = reinterpret_cast<const float2*>(cp + r1 * 10);
#pragma unroll
    for (int k = 0; k < 5; ++k){ float2 v = p[k]; cn[2*k]=v.x; cn[2*k+1]=v.y; }
    p = reinterpret_cast<const float2*>(cp + r2 * 10);
#pragma unroll
    for (int k = 0; k < 5; ++k){ float2 v = p[k]; cnn[2*k]=v.x; cnn[2*k+1]=v.y; }
  }

  // ---- deltas d_i (rows i,i+1) and d_{i+1} (rows i+1,i+2), all local ----
  float d[10], dn[10];
  float dsq = 0.f, dsqn = 0.f, dot = 0.f;
#pragma unroll
  for (int k = 0; k < 10; ++k) {
    float a = cn[k] - c[k];   d[k]  = a;  dsq  = fmaf(a, a, dsq);
    float e = cnn[k] - cn[k]; dn[k] = e;  dsqn = fmaf(e, e, dsqn);
    dot = fmaf(a, e, dot);
  }
  const float sn   = (dsq  > 0.f) ? fsq(fmaxf(dsq,  1e-30f)) : 0.f;  // safe_norm
  const float snn  = (dsqn > 0.f) ? fsq(fmaxf(dsqn, 1e-30f)) : 0.f;
  const float inv  = frcp(fmaxf(sn,  1e-8f));
  const float invn = frcp(fmaxf(snn, 1e-8f));

  const bool dact = (i < m);
  const float dm  = dact ? sn  : 0.f;
  const bool cact = (i < n - 2);
  const float cosv   = dot * inv * invn;
  const float cm     = cact ? cosv : 0.f;
  const float curv_m = cact ? (1.f - cosv) : 0.f;

  // ---- coord stats (rows < n) ----
  float csl = 0.f, cs2l = 0.f;
#pragma unroll
  for (int k = 0; k < 10; ++k) { csl += c[k]; cs2l = fmaf(c[k], c[k], cs2l); }
  const bool ract = (i < n);
  csl  = ract ? csl  : 0.f;
  cs2l = ract ? cs2l : 0.f;

  // ---- total displacement: lane m's ||c - c0||^2, via SGPR c0 broadcast ----
  float tql = 0.f;
#pragma unroll
  for (int k = 0; k < 10; ++k) {
    float t = c[k] - rld(c[k], 0);
    tql = fmaf(t, t, tql);
  }
  const float tsq = rld(tql, m);                       // uniform scalar
  const float total_disp = (tsq > 0.f) ? fsq(fmaxf(tsq, 1e-30f)) : 0.f;

  // ---- 22 reductions (lane-63-valid, no broadcast) ----
  const float path_len = wsum63(dm);
  const float sum_dm2  = wsum63(dact ? dsq : 0.f);
  const float max_dm   = wmax63(dm);
  const float sum_f    = wsum63((i <= half) ? dm : 0.f);
  const float dm_half  = rld(dm, half);
  const float sum_cos  = wsum63(cm);
  const float sum_cos2 = wsum63(cm * cm);
  const float max_cos  = wmax63(cact ? cosv : -INFINITY);
  const float min_cos  = wmin63(cact ? cosv :  INFINITY);
  const float sum_ng   = wsum63((cact && cosv < 0.f) ? 1.f : 0.f);
  const float sum_c    = wsum63(csl);
  const float sum_c2   = wsum63(cs2l);
  const float invm = dact ? inv : 0.f;
  float Usq = 0.f;
#pragma unroll
  for (int k = 0; k < 10; ++k) {
    float Uk = wsum63(d[k] * invm);
    Usq = fmaf(Uk, Uk, Usq);
  }
  const float sum_uu = wsum63(dsq * invm * invm);

  // ---- scalar features: computed on all lanes, VALID ON LANE 63 ----
  const float EPSf = 1e-9f;
  const float nf = (float)n, mf = (float)m, ncf = (float)(n - 2);
  const float rncf = frcp(ncf);
  const float sum_s = path_len + dm_half - sum_f;
  const float disp_ratio = total_disp * frcp(path_len + EPSf);
  const float mean_cv = (ncf - sum_cos) * rncf;
  const float sum_cv2 = fmaf(-2.f, sum_cos, ncf) + sum_cos2;
  const float cv_var  = (sum_cv2 - ncf * mean_cv * mean_cv) * frcp(fmaxf(ncf - 1.f, 1.f));
  const float std_cv  = fsq(fmaxf(cv_var, 1e-30f));
  const float fh = sum_f * frcp((float)(half + 1));
  const float sh = sum_s * frcp((float)(m - half));
  const float conv = (fh - sh) * frcp(fh + EPSf);
  const float npairs = mf * (mf - 1.f) * 0.5f;
  const float par = (Usq - sum_uu) * 0.5f * frcp(npairs);
  const float mean_dm = path_len * frcp(mf);
  const float dm_var = (sum_dm2 - mf * mean_dm * mean_dm) * frcp(mf - 1.f);
  const float std_dm = fsq(fmaxf(dm_var, 1e-30f));
  const float jump = (mean_dm > EPSf) ? max_dm * frcp(mean_dm) : 1.f;
  const float cnt = nf * 10.f;
  const float mean_co = sum_c * frcp(cnt);
  const float co_var = (sum_c2 - cnt * mean_co * mean_co) * frcp(cnt - 1.f);
  const float std_co = fsq(fmaxf(co_var, 1e-30f));

  // ---- 60 features -> SGPRs via readlane (scalars from lane 63) ----
  float feat[60];
  feat[0]  = rld(total_disp, 63);
  feat[1]  = rld(path_len, 63);
  feat[2]  = rld(disp_ratio, 63);
  feat[3]  = nf * 0.1f;
  feat[4]  = rld(mean_cv, 63);
  feat[5]  = 1.f - rld(min_cos, 63);       // max_curv
  feat[6]  = rld(std_cv, 63);
  feat[7]  = rld(max_cos - min_cos, 63);   // curv_range
  feat[8]  = rld(sum_cos * rncf, 63);      // mean_cos
  feat[9]  = rld(min_cos, 63);
  feat[10] = rld(sum_ng * rncf, 63);       // dir_changes
  feat[11] = feat[2];                      // linearity
  feat[12] = 1.f - feat[2];                // loop_score
  feat[13] = rld(conv, 63);
  feat[14] = rld(par, 63);
  feat[15] = rld(jump, 63);
  feat[16] = -feat[13];                    // cascade
  feat[17] = rld(mean_dm, 63);
  feat[18] = rld(std_dm, 63);
  feat[19] = rld(mean_co, 63);
  feat[20] = rld(std_co, 63);
#pragma unroll
  for (int k = 0; k < 10; ++k) feat[21 + k] = rld(d[k], 0);   // padded_deltas rows 0..2
#pragma unroll
  for (int k = 0; k < 10; ++k) feat[31 + k] = rld(d[k], 1);
#pragma unroll
  for (int k = 0; k < 10; ++k) feat[41 + k] = rld(d[k], 2);
#pragma unroll
  for (int r = 0; r < 9; ++r)  feat[51 + r] = rld(curv_m, r); // padded_curvs

  // ---- h_i = feat @ W + b (lane i computes output i; lanes >=48 clamped, discarded) ----
  const int jc = (i < 48) ? i : 47;
  float h = bias[jc];
  if (USEWT) {
    const float4* wr = reinterpret_cast<const float4*>(Wsrc + jc * 60);
#pragma unroll
    for (int t = 0; t < 15; ++t) {
      float4 w = wr[t];
      h = fmaf(feat[4*t+0], w.x, h);
      h = fmaf(feat[4*t+1], w.y, h);
      h = fmaf(feat[4*t+2], w.z, h);
      h = fmaf(feat[4*t+3], w.w, h);
    }
  } else {
#pragma unroll
    for (int f = 0; f < 60; ++f) h = fmaf(feat[f], Wsrc[f * 48 + jc], h);
  }

  // ---- LayerNorm over 48 outputs + tanh-GELU ----
  const float hm = (i < 48) ? h : 0.f;
  const float s1 = rld(wsum63(hm), 63);
  const float s2 = rld(wsum63(hm * hm), 63);
  const float mu  = s1 * (1.f / 48.f);
  const float var = fmaf(-mu, mu, s2 * (1.f / 48.f));
  const float rstd = __builtin_amdgcn_rsqf(var + 1e-5f);

  if (i < 48) {
    float x = (h - mu) * rstd * lnw[i] + lnb[i];
    float x2 = x * x;
    float u  = 0.7978845608f * x * fmaf(0.044715f, x2, 1.f);
    float e  = __builtin_amdgcn_exp2f(u * 2.885390082f);   // e^{2u}
    float th = fmaf(-2.f, frcp(1.f + e), 1.f);
    out[(size_t)b * 48 + i] = 0.5f * x * (1.f + th);
  }
}

extern "C" void kernel_launch(void* const* d_in, const int* in_sizes, int n_in,
                              void* d_out, int out_size, void* d_ws, size_t ws_size,
                              hipStream_t stream)
{
  const float* coords = (const float*)d_in[0];
  const int*   lengths= (const int*)d_in[1];
  const float* W      = (const float*)d_in[2];
  const float* bias   = (const float*)d_in[3];
  const float* lnw    = (const float*)d_in[4];
  const float* lnb    = (const float*)d_in[5];
  float* out = (float*)d_out;

  const int B = in_sizes[1];                 // 32768 trajectories
  const int blocks = (B + WPB - 1) / WPB;

  if (ws_size >= (size_t)(60 * 48 * sizeof(float))) {
    float* Wt = (float*)d_ws;
    transpose_w<<<12, 256, 0, stream>>>(W, Wt);
    traj_kernel<true><<<blocks, WPB * 64, 0, stream>>>(coords, lengths, Wt, bias, lnw, lnb, out, B);
  } else {
    traj_kernel<false><<<blocks, WPB * 64, 0, stream>>>(coords, lengths, W, bias, lnw, lnb, out, B);
  }
}